// Round 3
// baseline (172.136 us; speedup 1.0000x reference)
//
#include <hip/hip_runtime.h>
#include <hip/hip_bf16.h>

// NonlocalBlock: B=4, C=64, H=W=96 (N=9216), Ci=32, COMPRESSION=2 (M=4608).
// R3: S^T-form flash attention (C-layout => m-contiguous P), no K/V LDS
//     staging (phi/gT layouts are fragment-contiguous for direct global
//     b128 loads), zero in-loop barriers, split-K with f32 atomicAdd
//     partials (ws-size independent), MFMA-based reduce/out-projection.

#define NQ 9216
#define MM 4608
#define LOG2E 1.44269504088896340736f

typedef __attribute__((ext_vector_type(8))) short bf16x8;   // 8 bf16, 4 VGPRs
typedef __attribute__((ext_vector_type(4))) float f32x4;    // MFMA C/D
typedef __attribute__((ext_vector_type(4))) unsigned short u16x4;

static __device__ __forceinline__ unsigned short f2bf(float f) {
    unsigned u = __float_as_uint(f);
    unsigned r = (u + 0x7fffu + ((u >> 16) & 1u)) >> 16;   // RNE
    return (unsigned short)r;
}
static __device__ __forceinline__ unsigned pk2(float a, float b) {
    __hip_bfloat162 h = __float22bfloat162_rn(make_float2(a, b));
    return *reinterpret_cast<unsigned*>(&h);   // low16=a, high16=b
}

// ---------------------------------------------------------------------------
// Kernel 1: projections (unchanged from R2). 576 blocks x 256 thr.
// theta pre-scaled by LOG2E; phi [m][ci]; gT [ci][m] via LDS transpose.
// ---------------------------------------------------------------------------
__global__ __launch_bounds__(256) void proj_kernel(
    const float* __restrict__ x,
    const float* __restrict__ wt, const float* __restrict__ bt,
    const float* __restrict__ wp, const float* __restrict__ bp,
    const float* __restrict__ wg, const float* __restrict__ bg,
    unsigned short* __restrict__ theta, unsigned short* __restrict__ phi,
    unsigned short* __restrict__ gT)
{
    __shared__ unsigned short gst[32 * 36];

    const int tid  = threadIdx.x;
    const int wid  = tid >> 6;
    const int lane = tid & 63;
    const int q = lane >> 4;
    const int c = lane & 15;

    const int b     = blockIdx.x / 144;
    const int n0blk = (blockIdx.x % 144) * 64;
    const int n0    = n0blk + wid * 16;

    const float* Wm[3] = {wt, wp, wg};
    const float* Bm[3] = {bt, bp, bg};

    bf16x8 wf[3][2][2];
    float bias[3][2];
#pragma unroll
    for (int p = 0; p < 3; ++p) {
#pragma unroll
        for (int ct = 0; ct < 2; ++ct) {
            bias[p][ct] = Bm[p][ct * 16 + c];
#pragma unroll
            for (int ks = 0; ks < 2; ++ks) {
                const float* wsrc = Wm[p] + (ct * 16 + c) * 64 + ks * 32 + q * 8;
                f32x4 w0 = *(const f32x4*)wsrc;
                f32x4 w1 = *(const f32x4*)(wsrc + 4);
                unsigned short* wk = (unsigned short*)&wf[p][ct][ks];
#pragma unroll
                for (int j = 0; j < 4; ++j) { wk[j] = f2bf(w0[j]); wk[4 + j] = f2bf(w1[j]); }
            }
        }
    }

    bf16x8 af[2];
#pragma unroll
    for (int ks = 0; ks < 2; ++ks) {
        unsigned short* ap = (unsigned short*)&af[ks];
#pragma unroll
        for (int j = 0; j < 8; ++j)
            ap[j] = f2bf(x[(b * 64 + ks * 32 + q * 8 + j) * NQ + n0 + c]);
    }

#pragma unroll
    for (int p = 0; p < 3; ++p) {
#pragma unroll
        for (int ct = 0; ct < 2; ++ct) {
            f32x4 acc = {0.f, 0.f, 0.f, 0.f};
            acc = __builtin_amdgcn_mfma_f32_16x16x32_bf16(af[0], wf[p][ct][0], acc, 0, 0, 0);
            acc = __builtin_amdgcn_mfma_f32_16x16x32_bf16(af[1], wf[p][ct][1], acc, 0, 0, 0);
#pragma unroll
            for (int r = 0; r < 4; ++r) acc[r] += bias[p][ct];
            const int ci = ct * 16 + c;
            if (p == 0) {
#pragma unroll
                for (int r = 0; r < 4; ++r)
                    theta[(b * NQ + n0 + 4 * q + r) * 32 + ci] = f2bf(acc[r] * LOG2E);
            } else {
                float v0 = fmaxf(acc[0], acc[1]);
                float v1 = fmaxf(acc[2], acc[3]);
                if (p == 1) {
                    const int m0 = (n0 >> 1) + 2 * q;
                    phi[(b * MM + m0) * 32 + ci]     = f2bf(v0);
                    phi[(b * MM + m0 + 1) * 32 + ci] = f2bf(v1);
                } else {
                    *(unsigned int*)(gst + ci * 36 + wid * 8 + 2 * q) =
                        (unsigned int)f2bf(v0) | ((unsigned int)f2bf(v1) << 16);
                }
            }
        }
    }

    __syncthreads();
    {
        const int t  = tid & 255;
        const int ci = t >> 3;
        const int m4 = (t & 7) * 4;
        u16x4 v = *(const u16x4*)(gst + ci * 36 + m4);
        *(u16x4*)(gT + (b * 32 + ci) * MM + (n0blk >> 1) + m4) = v;
    }
}

// ---------------------------------------------------------------------------
// Kernel 2: split-K flash attention, S^T formulation, no barriers.
// Grid: KS*576 blocks x 128 thr (2 waves x 32 q-rows). mtpc M-tiles each.
// Partials accumulated into pacc[b][ci][n] / plsum[b][n] via atomicAdd.
// ---------------------------------------------------------------------------
__global__ __launch_bounds__(128, 6) void attn_kernel(
    const unsigned short* __restrict__ theta, const unsigned short* __restrict__ phi,
    const unsigned short* __restrict__ gT,
    float* __restrict__ pacc, float* __restrict__ plsum, int mtpc)
{
    __shared__ unsigned short pld[2][32 * 72];   // per-wave P^T: [n 32][m 64+8]

    const int tid  = threadIdx.x;
    const int w    = tid >> 6;
    const int lane = tid & 63;
    const int q = lane >> 4;
    const int c = lane & 15;

    const int ks  = blockIdx.x / 576;
    const int rem = blockIdx.x % 576;
    const int b   = rem / 144;
    const int nb  = (rem % 144) * 64 + w * 32;

    // Q B-frags: B[k=ch][col n]: theta[n][ch], n=c within rt-tile, ch=q*8+j
    bf16x8 qf[2];
#pragma unroll
    for (int rt = 0; rt < 2; ++rt)
        qf[rt] = *(const bf16x8*)(theta + (b * NQ + nb + rt * 16 + c) * 32 + q * 8);

    const unsigned short* phiB = phi + (size_t)b * MM * 32;
    const unsigned short* gTB  = gT + (size_t)b * 32 * MM;
    unsigned short* myp = pld[w];

    f32x4 acc[2][2];   // [rt n-tile][s2 ci-tile], C-layout: col=n, row=ci
    float lsum[2] = {0.f, 0.f};
#pragma unroll
    for (int rt = 0; rt < 2; ++rt)
#pragma unroll
        for (int s2 = 0; s2 < 2; ++s2) acc[rt][s2] = (f32x4){0.f, 0.f, 0.f, 0.f};

    const int mt0 = ks * mtpc;
    for (int mi = 0; mi < mtpc; ++mi) {
        const int m0 = (mt0 + mi) * 64;

        // V^T A-frags direct from global: A[ci][k=m]
        bf16x8 vf[2][2];
#pragma unroll
        for (int s2 = 0; s2 < 2; ++s2)
#pragma unroll
            for (int st = 0; st < 2; ++st)
                vf[s2][st] = *(const bf16x8*)(gTB + (s2 * 16 + c) * MM + m0 + st * 32 + q * 8);

        // S^T = phi . theta^T per m-subtile; exp2; P^T rows -> LDS (b64)
#pragma unroll
        for (int mct = 0; mct < 4; ++mct) {
            // phi A-frag: A[m][k=ch] (direct global, fragment-contiguous)
            bf16x8 kf = *(const bf16x8*)(phiB + (m0 + mct * 16 + c) * 32 + q * 8);
#pragma unroll
            for (int rt = 0; rt < 2; ++rt) {
                f32x4 z = {0.f, 0.f, 0.f, 0.f};
                f32x4 s = __builtin_amdgcn_mfma_f32_16x16x32_bf16(kf, qf[rt], z, 0, 0, 0);
                float p0 = __builtin_amdgcn_exp2f(s[0]);
                float p1 = __builtin_amdgcn_exp2f(s[1]);
                float p2 = __builtin_amdgcn_exp2f(s[2]);
                float p3 = __builtin_amdgcn_exp2f(s[3]);
                lsum[rt] += (p0 + p1) + (p2 + p3);
                uint2 hv = {pk2(p0, p1), pk2(p2, p3)};
                // lane holds col n=c, rows m=mct*16+4q+r -> pld[n][m] contiguous
                *(uint2*)(myp + (rt * 16 + c) * 72 + mct * 16 + 4 * q) = hv;
            }
        }
        // PV: acc^T += V^T . P^T  (P^T B-frags: b128, k=m contiguous)
#pragma unroll
        for (int rt = 0; rt < 2; ++rt) {
#pragma unroll
            for (int st = 0; st < 2; ++st) {
                bf16x8 pf = *(const bf16x8*)(myp + (rt * 16 + c) * 72 + st * 32 + q * 8);
#pragma unroll
                for (int s2 = 0; s2 < 2; ++s2)
                    acc[rt][s2] = __builtin_amdgcn_mfma_f32_16x16x32_bf16(vf[s2][st], pf, acc[rt][s2], 0, 0, 0);
            }
        }
    }

    // denominator: sum across the 4 quads (lanes c, c+16, c+32, c+48)
#pragma unroll
    for (int rt = 0; rt < 2; ++rt) {
        lsum[rt] += __shfl_xor(lsum[rt], 16);
        lsum[rt] += __shfl_xor(lsum[rt], 32);
    }

    // accumulate partials: pacc[b][ci][n] coalesced per quad-row
#pragma unroll
    for (int rt = 0; rt < 2; ++rt)
#pragma unroll
        for (int s2 = 0; s2 < 2; ++s2)
#pragma unroll
            for (int r = 0; r < 4; ++r)
                atomicAdd(&pacc[(size_t)(b * 32 + s2 * 16 + 4 * q + r) * NQ + nb + rt * 16 + c],
                          acc[rt][s2][r]);
    if (lane < 16) {
#pragma unroll
        for (int rt = 0; rt < 2; ++rt)
            atomicAdd(&plsum[(size_t)b * NQ + nb + rt * 16 + lane], lsum[rt]);
    }
}

// ---------------------------------------------------------------------------
// Kernel 3: y^T = pacc/plsum -> LDS [ci][n] tile -> out = w_out.y^T + b + x.
// Grid: 576 blocks x 256 thr (4 waves x 16 n).
// ---------------------------------------------------------------------------
__global__ __launch_bounds__(256) void reduce_kernel(
    const float* __restrict__ pacc, const float* __restrict__ plsum,
    const float* __restrict__ w_out, const float* __restrict__ b_out,
    const float* __restrict__ x, float* __restrict__ out)
{
    __shared__ unsigned short yld[32 * 68];   // y^T tile: [ci 32][n 64+4]

    const int tid = threadIdx.x;
    const int b   = blockIdx.x / 144;
    const int nb  = (blockIdx.x % 144) * 64;

    // phase 1: coalesced read of pacc/plsum, divide, bf16, stage to LDS
    {
        const int ci = tid >> 3;
        const int n8 = (tid & 7) * 8;
        const float* pr = pacc + (size_t)(b * 32 + ci) * NQ + nb + n8;
        f32x4 a0 = *(const f32x4*)pr;
        f32x4 a1 = *(const f32x4*)(pr + 4);
        const float* lr = plsum + (size_t)b * NQ + nb + n8;
        f32x4 l0 = *(const f32x4*)lr;
        f32x4 l1 = *(const f32x4*)(lr + 4);
        uint2 v0 = {pk2(a0[0] / l0[0], a0[1] / l0[1]), pk2(a0[2] / l0[2], a0[3] / l0[3])};
        uint2 v1 = {pk2(a1[0] / l1[0], a1[1] / l1[1]), pk2(a1[2] / l1[2], a1[3] / l1[3])};
        *(uint2*)(yld + ci * 68 + n8)     = v0;
        *(uint2*)(yld + ci * 68 + n8 + 4) = v1;
    }
    __syncthreads();

    // phase 2: out-projection MFMA. A=w_out (rows chn, k=ci), B=y^T.
    const int w    = tid >> 6;
    const int lane = tid & 63;
    const int q = lane >> 4;
    const int c = lane & 15;

    bf16x8 wof[4];
#pragma unroll
    for (int ct = 0; ct < 4; ++ct) {
        const float* wsrc = w_out + (ct * 16 + c) * 32 + q * 8;
        f32x4 w0 = *(const f32x4*)wsrc;
        f32x4 w1 = *(const f32x4*)(wsrc + 4);
        unsigned* wk = (unsigned*)&wof[ct];
        wk[0] = pk2(w0[0], w0[1]); wk[1] = pk2(w0[2], w0[3]);
        wk[2] = pk2(w1[0], w1[1]); wk[3] = pk2(w1[2], w1[3]);
    }

    // B-frag: B[k=ci=q*8+j][col n=w*16+c] from yld[ci][n]
    bf16x8 yf;
    {
        unsigned short* yp = (unsigned short*)&yf;
#pragma unroll
        for (int j = 0; j < 8; ++j)
            yp[j] = yld[(q * 8 + j) * 68 + w * 16 + c];
    }

#pragma unroll
    for (int ct = 0; ct < 4; ++ct) {
        f32x4 z = {0.f, 0.f, 0.f, 0.f};
        f32x4 o = __builtin_amdgcn_mfma_f32_16x16x32_bf16(wof[ct], yf, z, 0, 0, 0);
#pragma unroll
        for (int r = 0; r < 4; ++r) {
            const int chn = ct * 16 + 4 * q + r;
            const size_t addr = (size_t)(b * 64 + chn) * NQ + nb + w * 16 + c;
            out[addr] = o[r] + b_out[chn] + x[addr];
        }
    }
}

extern "C" void kernel_launch(void* const* d_in, const int* in_sizes, int n_in,
                              void* d_out, int out_size, void* d_ws, size_t ws_size,
                              hipStream_t stream) {
    const float* x       = (const float*)d_in[0];
    const float* w_theta = (const float*)d_in[1];
    const float* b_theta = (const float*)d_in[2];
    const float* w_phi   = (const float*)d_in[3];
    const float* b_phi   = (const float*)d_in[4];
    const float* w_g     = (const float*)d_in[5];
    const float* b_g     = (const float*)d_in[6];
    const float* w_out   = (const float*)d_in[7];
    const float* b_out   = (const float*)d_in[8];
    float* out = (float*)d_out;

    // ws layout (bytes):
    //   theta bf16 [4][9216][32] : 2,359,296
    //   phi   bf16 [4][4608][32] : 1,179,648
    //   gT    bf16 [4][32][4608] : 1,179,648
    //   pacc  f32  [4][32][9216] : 4,718,592   (atomic accumulators)
    //   plsum f32  [4][9216]     :   147,456
    // total 9.58 MB — fits any plausible ws_size; KS needs no ladder.
    unsigned short* theta = (unsigned short*)d_ws;
    unsigned short* phi   = theta + 4 * NQ * 32;
    unsigned short* gT    = phi + 4 * MM * 32;
    float* pacc  = (float*)(gT + 4 * 32 * MM);
    float* plsum = pacc + (size_t)4 * 32 * NQ;

    hipMemsetAsync(pacc, 0, (size_t)(4 * 32 * NQ + 4 * NQ) * sizeof(float), stream);

    const int KS = 8;                 // 72 M-tiles -> 9 per chunk
    proj_kernel<<<576, 256, 0, stream>>>(x, w_theta, b_theta, w_phi, b_phi,
                                         w_g, b_g, theta, phi, gT);
    attn_kernel<<<KS * 576, 128, 0, stream>>>(theta, phi, gT, pacc, plsum, 72 / KS);
    reduce_kernel<<<576, 256, 0, stream>>>(pacc, plsum, w_out, b_out, x, out);
}

// Round 4
// 153.404 us; speedup vs baseline: 1.1221x; 1.1221x over previous
//
#include <hip/hip_runtime.h>
#include <hip/hip_bf16.h>

// NonlocalBlock: B=4, C=64, H=W=96 (N=9216), Ci=32, COMPRESSION=2 (M=4608).
// R4: attn reworked for per-wave ILP: 64 q-rows/wave (32 MFMA/tile), kf
//     software-pipelined (prefetch next tile), XOR-swizzled P^T LDS
//     (2-way writes, b128 reads), KS=8 split-K with f32 atomic partials.
//     proj zero-fills the partial buffers (no memset dispatch) and builds
//     fragments with packed bf16 converts.

#define NQ 9216
#define MM 4608
#define LOG2E 1.44269504088896340736f

typedef __attribute__((ext_vector_type(8))) short bf16x8;   // 8 bf16, 4 VGPRs
typedef __attribute__((ext_vector_type(4))) float f32x4;    // MFMA C/D
typedef __attribute__((ext_vector_type(4))) unsigned short u16x4;

static __device__ __forceinline__ unsigned short f2bf(float f) {
    unsigned u = __float_as_uint(f);
    unsigned r = (u + 0x7fffu + ((u >> 16) & 1u)) >> 16;   // RNE
    return (unsigned short)r;
}
static __device__ __forceinline__ unsigned pk2(float a, float b) {
    __hip_bfloat162 h = __float22bfloat162_rn(make_float2(a, b));
    return *reinterpret_cast<unsigned*>(&h);   // low16=a, high16=b
}

// ---------------------------------------------------------------------------
// Kernel 1: projections + zero-fill of partial buffers. 576 blocks x 256 thr.
// theta pre-scaled by LOG2E; phi [m][ci]; gT [ci][m] via LDS transpose.
// ---------------------------------------------------------------------------
__global__ __launch_bounds__(256) void proj_kernel(
    const float* __restrict__ x,
    const float* __restrict__ wt, const float* __restrict__ bt,
    const float* __restrict__ wp, const float* __restrict__ bp,
    const float* __restrict__ wg, const float* __restrict__ bg,
    unsigned short* __restrict__ theta, unsigned short* __restrict__ phi,
    unsigned short* __restrict__ gT, float* __restrict__ pzero)
{
    __shared__ unsigned short gst[32 * 36];

    const int tid  = threadIdx.x;
    const int wid  = tid >> 6;
    const int lane = tid & 63;
    const int q = lane >> 4;
    const int c = lane & 15;

    // zero pacc+plsum (contiguous): 1,216,512 floats = 304,128 float4
    {
        const int gs = gridDim.x * blockDim.x;
        float4 z4 = {0.f, 0.f, 0.f, 0.f};
        for (int i = blockIdx.x * blockDim.x + tid; i < 304128; i += gs)
            ((float4*)pzero)[i] = z4;
    }

    const int b     = blockIdx.x / 144;
    const int n0blk = (blockIdx.x % 144) * 64;
    const int n0    = n0blk + wid * 16;

    const float* Wm[3] = {wt, wp, wg};
    const float* Bm[3] = {bt, bp, bg};

    bf16x8 wf[3][2][2];
    float bias[3][2];
#pragma unroll
    for (int p = 0; p < 3; ++p) {
#pragma unroll
        for (int ct = 0; ct < 2; ++ct) {
            bias[p][ct] = Bm[p][ct * 16 + c];
#pragma unroll
            for (int ks = 0; ks < 2; ++ks) {
                const float* wsrc = Wm[p] + (ct * 16 + c) * 64 + ks * 32 + q * 8;
                f32x4 w0 = *(const f32x4*)wsrc;
                f32x4 w1 = *(const f32x4*)(wsrc + 4);
                unsigned* wk = (unsigned*)&wf[p][ct][ks];
                wk[0] = pk2(w0[0], w0[1]); wk[1] = pk2(w0[2], w0[3]);
                wk[2] = pk2(w1[0], w1[1]); wk[3] = pk2(w1[2], w1[3]);
            }
        }
    }

    bf16x8 af[2];
#pragma unroll
    for (int ks = 0; ks < 2; ++ks) {
        unsigned* ap = (unsigned*)&af[ks];
#pragma unroll
        for (int j2 = 0; j2 < 4; ++j2) {
            float x0 = x[(b * 64 + ks * 32 + q * 8 + j2 * 2) * NQ + n0 + c];
            float x1 = x[(b * 64 + ks * 32 + q * 8 + j2 * 2 + 1) * NQ + n0 + c];
            ap[j2] = pk2(x0, x1);
        }
    }

#pragma unroll
    for (int p = 0; p < 3; ++p) {
#pragma unroll
        for (int ct = 0; ct < 2; ++ct) {
            f32x4 acc = {0.f, 0.f, 0.f, 0.f};
            acc = __builtin_amdgcn_mfma_f32_16x16x32_bf16(af[0], wf[p][ct][0], acc, 0, 0, 0);
            acc = __builtin_amdgcn_mfma_f32_16x16x32_bf16(af[1], wf[p][ct][1], acc, 0, 0, 0);
#pragma unroll
            for (int r = 0; r < 4; ++r) acc[r] += bias[p][ct];
            const int ci = ct * 16 + c;
            if (p == 0) {
                unsigned pv0 = pk2(acc[0] * LOG2E, acc[1] * LOG2E);
                unsigned pv1 = pk2(acc[2] * LOG2E, acc[3] * LOG2E);
                theta[(b * NQ + n0 + 4 * q + 0) * 32 + ci] = (unsigned short)pv0;
                theta[(b * NQ + n0 + 4 * q + 1) * 32 + ci] = (unsigned short)(pv0 >> 16);
                theta[(b * NQ + n0 + 4 * q + 2) * 32 + ci] = (unsigned short)pv1;
                theta[(b * NQ + n0 + 4 * q + 3) * 32 + ci] = (unsigned short)(pv1 >> 16);
            } else {
                unsigned pv = pk2(fmaxf(acc[0], acc[1]), fmaxf(acc[2], acc[3]));
                if (p == 1) {
                    const int m0 = (n0 >> 1) + 2 * q;
                    phi[(b * MM + m0) * 32 + ci]     = (unsigned short)pv;
                    phi[(b * MM + m0 + 1) * 32 + ci] = (unsigned short)(pv >> 16);
                } else {
                    *(unsigned int*)(gst + ci * 36 + wid * 8 + 2 * q) = pv;
                }
            }
        }
    }

    __syncthreads();
    {
        const int t  = tid & 255;
        const int ci = t >> 3;
        const int m4 = (t & 7) * 4;
        u16x4 v = *(const u16x4*)(gst + ci * 36 + m4);
        *(u16x4*)(gT + (b * 32 + ci) * MM + (n0blk >> 1) + m4) = v;
    }
}

// ---------------------------------------------------------------------------
// Kernel 2: split-K flash attention, S^T form, 64 q-rows/wave, kf pipelined.
// Grid: KS(=8)*288 blocks x 128 thr (2 waves). 9 M-tiles per block.
// Partials accumulated into pacc[b][ci][n] / plsum[b][n] via atomicAdd.
// ---------------------------------------------------------------------------
__global__ __launch_bounds__(128, 4) void attn_kernel(
    const unsigned short* __restrict__ theta, const unsigned short* __restrict__ phi,
    const unsigned short* __restrict__ gT,
    float* __restrict__ pacc, float* __restrict__ plsum)
{
    __shared__ unsigned short pld[2][64 * 64];   // per-wave P^T [n 64][m 64], XOR-swizzled

    const int tid  = threadIdx.x;
    const int w    = tid >> 6;
    const int lane = tid & 63;
    const int q  = lane >> 4;
    const int c  = lane & 15;
    const int xr = (c & 7) << 3;   // XOR swizzle for the m index

    const int ks  = blockIdx.x / 288;            // 0..7
    const int rem = blockIdx.x % 288;
    const int b   = rem / 72;
    const int nb  = (rem % 72) * 128 + w * 64;   // this wave's first Q row

    // Q B-frags: theta[n][ch], lane col n = c (per rt tile), k = q*8+j
    bf16x8 qf[4];
#pragma unroll
    for (int rt = 0; rt < 4; ++rt)
        qf[rt] = *(const bf16x8*)(theta + (b * NQ + nb + rt * 16 + c) * 32 + q * 8);

    const unsigned short* phiB = phi + (size_t)b * MM * 32;
    const unsigned short* gTB  = gT + (size_t)b * 32 * MM;
    unsigned short* myp = pld[w];

    f32x4 acc[4][2];   // [rt n-tile][s2 ci-tile]: col=n, row=ci
    float lsum[4] = {0.f, 0.f, 0.f, 0.f};
#pragma unroll
    for (int rt = 0; rt < 4; ++rt)
#pragma unroll
        for (int s2 = 0; s2 < 2; ++s2) acc[rt][s2] = (f32x4){0.f, 0.f, 0.f, 0.f};

    const int mt0 = ks * 9;
    // prefetch kf (phi A-frags) for the first tile
    bf16x8 kf[4];
#pragma unroll
    for (int mct = 0; mct < 4; ++mct)
        kf[mct] = *(const bf16x8*)(phiB + (mt0 * 64 + mct * 16 + c) * 32 + q * 8);

    for (int mi = 0; mi < 9; ++mi) {
        const int m0  = (mt0 + mi) * 64;
        const int m0n = (mt0 + (mi < 8 ? mi + 1 : mi)) * 64;   // clamped dup on last

        // V^T A-frags for this tile (consumed late -> latency self-hidden)
        bf16x8 vf[2][2];
#pragma unroll
        for (int s2 = 0; s2 < 2; ++s2)
#pragma unroll
            for (int st = 0; st < 2; ++st)
                vf[s2][st] = *(const bf16x8*)(gTB + (s2 * 16 + c) * MM + m0 + st * 32 + q * 8);

        // prefetch next tile's kf
        bf16x8 kn[4];
#pragma unroll
        for (int mct = 0; mct < 4; ++mct)
            kn[mct] = *(const bf16x8*)(phiB + (m0n + mct * 16 + c) * 32 + q * 8);

        // S^T = phi . theta^T; exp2; P^T -> LDS (XOR-swizzled, 2-way writes)
#pragma unroll
        for (int mct = 0; mct < 4; ++mct) {
#pragma unroll
            for (int rt = 0; rt < 4; ++rt) {
                f32x4 z = {0.f, 0.f, 0.f, 0.f};
                f32x4 s = __builtin_amdgcn_mfma_f32_16x16x32_bf16(kf[mct], qf[rt], z, 0, 0, 0);
                float p0 = __builtin_amdgcn_exp2f(s[0]);
                float p1 = __builtin_amdgcn_exp2f(s[1]);
                float p2 = __builtin_amdgcn_exp2f(s[2]);
                float p3 = __builtin_amdgcn_exp2f(s[3]);
                lsum[rt] += (p0 + p1) + (p2 + p3);
                uint2 hv = {pk2(p0, p1), pk2(p2, p3)};
                *(uint2*)(myp + ((rt * 16 + c) << 6) + ((mct * 16 + 4 * q) ^ xr)) = hv;
            }
        }
        // PV: acc^T += V^T . P^T (b128 reads, base and XOR both 8-aligned)
#pragma unroll
        for (int rt = 0; rt < 4; ++rt) {
#pragma unroll
            for (int st = 0; st < 2; ++st) {
                bf16x8 pf = *(const bf16x8*)(myp + ((rt * 16 + c) << 6) + ((st * 32 + q * 8) ^ xr));
#pragma unroll
                for (int s2 = 0; s2 < 2; ++s2)
                    acc[rt][s2] = __builtin_amdgcn_mfma_f32_16x16x32_bf16(vf[s2][st], pf, acc[rt][s2], 0, 0, 0);
            }
        }
#pragma unroll
        for (int mct = 0; mct < 4; ++mct) kf[mct] = kn[mct];
    }

    // denominator: sum across the 4 quads (lanes c, c+16, c+32, c+48)
#pragma unroll
    for (int rt = 0; rt < 4; ++rt) {
        lsum[rt] += __shfl_xor(lsum[rt], 16);
        lsum[rt] += __shfl_xor(lsum[rt], 32);
    }

    // accumulate partials: pacc[b][ci][n], 16-lane-contiguous per quad row
#pragma unroll
    for (int rt = 0; rt < 4; ++rt)
#pragma unroll
        for (int s2 = 0; s2 < 2; ++s2)
#pragma unroll
            for (int r = 0; r < 4; ++r)
                atomicAdd(&pacc[(size_t)(b * 32 + s2 * 16 + 4 * q + r) * NQ + nb + rt * 16 + c],
                          acc[rt][s2][r]);
    if (lane < 16) {
#pragma unroll
        for (int rt = 0; rt < 4; ++rt)
            atomicAdd(&plsum[(size_t)b * NQ + nb + rt * 16 + lane], lsum[rt]);
    }
}

// ---------------------------------------------------------------------------
// Kernel 3: y^T = pacc/plsum -> LDS [ci][n] tile -> out = w_out.y^T + b + x.
// Grid: 576 blocks x 256 thr (4 waves x 16 n).
// ---------------------------------------------------------------------------
__global__ __launch_bounds__(256) void reduce_kernel(
    const float* __restrict__ pacc, const float* __restrict__ plsum,
    const float* __restrict__ w_out, const float* __restrict__ b_out,
    const float* __restrict__ x, float* __restrict__ out)
{
    __shared__ unsigned short yld[32 * 68];   // y^T tile: [ci 32][n 64+4]

    const int tid = threadIdx.x;
    const int b   = blockIdx.x / 144;
    const int nb  = (blockIdx.x % 144) * 64;

    // phase 1: coalesced read of pacc/plsum, divide, bf16, stage to LDS
    {
        const int ci = tid >> 3;
        const int n8 = (tid & 7) * 8;
        const float* pr = pacc + (size_t)(b * 32 + ci) * NQ + nb + n8;
        f32x4 a0 = *(const f32x4*)pr;
        f32x4 a1 = *(const f32x4*)(pr + 4);
        const float* lr = plsum + (size_t)b * NQ + nb + n8;
        f32x4 l0 = *(const f32x4*)lr;
        f32x4 l1 = *(const f32x4*)(lr + 4);
        uint2 v0 = {pk2(a0[0] / l0[0], a0[1] / l0[1]), pk2(a0[2] / l0[2], a0[3] / l0[3])};
        uint2 v1 = {pk2(a1[0] / l1[0], a1[1] / l1[1]), pk2(a1[2] / l1[2], a1[3] / l1[3])};
        *(uint2*)(yld + ci * 68 + n8)     = v0;
        *(uint2*)(yld + ci * 68 + n8 + 4) = v1;
    }
    __syncthreads();

    // phase 2: out-projection MFMA. A=w_out (rows chn, k=ci), B=y^T.
    const int w    = tid >> 6;
    const int lane = tid & 63;
    const int q = lane >> 4;
    const int c = lane & 15;

    bf16x8 wof[4];
#pragma unroll
    for (int ct = 0; ct < 4; ++ct) {
        const float* wsrc = w_out + (ct * 16 + c) * 32 + q * 8;
        f32x4 w0 = *(const f32x4*)wsrc;
        f32x4 w1 = *(const f32x4*)(wsrc + 4);
        unsigned* wk = (unsigned*)&wof[ct];
        wk[0] = pk2(w0[0], w0[1]); wk[1] = pk2(w0[2], w0[3]);
        wk[2] = pk2(w1[0], w1[1]); wk[3] = pk2(w1[2], w1[3]);
    }

    // B-frag: B[k=ci=q*8+j][col n=w*16+c] from yld[ci][n]
    bf16x8 yf;
    {
        unsigned short* yp = (unsigned short*)&yf;
#pragma unroll
        for (int j = 0; j < 8; ++j)
            yp[j] = yld[(q * 8 + j) * 68 + w * 16 + c];
    }

#pragma unroll
    for (int ct = 0; ct < 4; ++ct) {
        f32x4 z = {0.f, 0.f, 0.f, 0.f};
        f32x4 o = __builtin_amdgcn_mfma_f32_16x16x32_bf16(wof[ct], yf, z, 0, 0, 0);
#pragma unroll
        for (int r = 0; r < 4; ++r) {
            const int chn = ct * 16 + 4 * q + r;
            const size_t addr = (size_t)(b * 64 + chn) * NQ + nb + w * 16 + c;
            out[addr] = o[r] + b_out[chn] + x[addr];
        }
    }
}

extern "C" void kernel_launch(void* const* d_in, const int* in_sizes, int n_in,
                              void* d_out, int out_size, void* d_ws, size_t ws_size,
                              hipStream_t stream) {
    const float* x       = (const float*)d_in[0];
    const float* w_theta = (const float*)d_in[1];
    const float* b_theta = (const float*)d_in[2];
    const float* w_phi   = (const float*)d_in[3];
    const float* b_phi   = (const float*)d_in[4];
    const float* w_g     = (const float*)d_in[5];
    const float* b_g     = (const float*)d_in[6];
    const float* w_out   = (const float*)d_in[7];
    const float* b_out   = (const float*)d_in[8];
    float* out = (float*)d_out;

    // ws layout (bytes):
    //   theta bf16 [4][9216][32] : 2,359,296
    //   phi   bf16 [4][4608][32] : 1,179,648
    //   gT    bf16 [4][32][4608] : 1,179,648
    //   pacc  f32  [4][32][9216] : 4,718,592   (atomic accumulators)
    //   plsum f32  [4][9216]     :   147,456   (contiguous with pacc)
    unsigned short* theta = (unsigned short*)d_ws;
    unsigned short* phi   = theta + 4 * NQ * 32;
    unsigned short* gT    = phi + 4 * MM * 32;
    float* pacc  = (float*)(gT + 4 * 32 * MM);
    float* plsum = pacc + (size_t)4 * 32 * NQ;

    proj_kernel<<<576, 256, 0, stream>>>(x, w_theta, b_theta, w_phi, b_phi,
                                         w_g, b_g, theta, phi, gT, pacc);
    attn_kernel<<<8 * 288, 128, 0, stream>>>(theta, phi, gT, pacc, plsum);
    reduce_kernel<<<576, 256, 0, stream>>>(pacc, plsum, w_out, b_out, x, out);
}

// Round 5
// 142.680 us; speedup vs baseline: 1.2064x; 1.0752x over previous
//
#include <hip/hip_runtime.h>
#include <hip/hip_bf16.h>

// NonlocalBlock: B=4, C=64, H=W=96 (N=9216), Ci=32, COMPRESSION=2 (M=4608).
// R5: in-wave software-pipelined attn (PV of tile i-1 overlaps exp2 of tile i;
//     single per-wave P buffer relying on same-wave in-order DS), lsum via
//     ones-row MFMA on the idle matrix pipe, proj/reduce re-geometried to
//     1152x128 for 2x wave count. KS=8 split-K with f32 atomic partials.

#define NQ 9216
#define MM 4608
#define LOG2E 1.44269504088896340736f

typedef __attribute__((ext_vector_type(8))) short bf16x8;   // 8 bf16, 4 VGPRs
typedef __attribute__((ext_vector_type(4))) float f32x4;    // MFMA C/D
typedef __attribute__((ext_vector_type(4))) unsigned short u16x4;

static __device__ __forceinline__ unsigned pk2(float a, float b) {
    __hip_bfloat162 h = __float22bfloat162_rn(make_float2(a, b));
    return *reinterpret_cast<unsigned*>(&h);   // low16=a, high16=b
}

// ---------------------------------------------------------------------------
// Kernel 1: projections + zero-fill of partial buffers. 1152 blocks x 128 thr
// (2 waves, 1 n-tile of 16 each). theta pre-scaled by LOG2E; phi [m][ci];
// gT [ci][m] via LDS transpose.
// ---------------------------------------------------------------------------
__global__ __launch_bounds__(128, 4) void proj_kernel(
    const float* __restrict__ x,
    const float* __restrict__ wt, const float* __restrict__ bt,
    const float* __restrict__ wp, const float* __restrict__ bp,
    const float* __restrict__ wg, const float* __restrict__ bg,
    unsigned short* __restrict__ theta, unsigned short* __restrict__ phi,
    unsigned short* __restrict__ gT, float* __restrict__ pzero)
{
    __shared__ unsigned short gst[32 * 20];   // [ci 32][m-local 16 +4]

    const int tid  = threadIdx.x;
    const int wid  = tid >> 6;
    const int lane = tid & 63;
    const int q = lane >> 4;
    const int c = lane & 15;

    // zero pacc+plsum (contiguous): 1,216,512 floats = 304,128 float4
    {
        const int gs = gridDim.x * blockDim.x;
        float4 z4 = {0.f, 0.f, 0.f, 0.f};
        for (int i = blockIdx.x * blockDim.x + tid; i < 304128; i += gs)
            ((float4*)pzero)[i] = z4;
    }

    const int b     = blockIdx.x / 288;
    const int rem   = blockIdx.x % 288;
    const int n0blk = rem * 32;
    const int n0    = n0blk + wid * 16;

    const float* Wm[3] = {wt, wp, wg};
    const float* Bm[3] = {bt, bp, bg};

    bf16x8 wf[3][2][2];
    float bias[3][2];
#pragma unroll
    for (int p = 0; p < 3; ++p) {
#pragma unroll
        for (int ct = 0; ct < 2; ++ct) {
            bias[p][ct] = Bm[p][ct * 16 + c];
#pragma unroll
            for (int ks = 0; ks < 2; ++ks) {
                const float* wsrc = Wm[p] + (ct * 16 + c) * 64 + ks * 32 + q * 8;
                f32x4 w0 = *(const f32x4*)wsrc;
                f32x4 w1 = *(const f32x4*)(wsrc + 4);
                unsigned* wk = (unsigned*)&wf[p][ct][ks];
                wk[0] = pk2(w0[0], w0[1]); wk[1] = pk2(w0[2], w0[3]);
                wk[2] = pk2(w1[0], w1[1]); wk[3] = pk2(w1[2], w1[3]);
            }
        }
    }

    bf16x8 af[2];
#pragma unroll
    for (int ks = 0; ks < 2; ++ks) {
        unsigned* ap = (unsigned*)&af[ks];
#pragma unroll
        for (int j2 = 0; j2 < 4; ++j2) {
            float x0 = x[(b * 64 + ks * 32 + q * 8 + j2 * 2) * NQ + n0 + c];
            float x1 = x[(b * 64 + ks * 32 + q * 8 + j2 * 2 + 1) * NQ + n0 + c];
            ap[j2] = pk2(x0, x1);
        }
    }

#pragma unroll
    for (int p = 0; p < 3; ++p) {
#pragma unroll
        for (int ct = 0; ct < 2; ++ct) {
            f32x4 acc = {0.f, 0.f, 0.f, 0.f};
            acc = __builtin_amdgcn_mfma_f32_16x16x32_bf16(af[0], wf[p][ct][0], acc, 0, 0, 0);
            acc = __builtin_amdgcn_mfma_f32_16x16x32_bf16(af[1], wf[p][ct][1], acc, 0, 0, 0);
#pragma unroll
            for (int r = 0; r < 4; ++r) acc[r] += bias[p][ct];
            const int ci = ct * 16 + c;
            if (p == 0) {
                unsigned pv0 = pk2(acc[0] * LOG2E, acc[1] * LOG2E);
                unsigned pv1 = pk2(acc[2] * LOG2E, acc[3] * LOG2E);
                theta[(b * NQ + n0 + 4 * q + 0) * 32 + ci] = (unsigned short)pv0;
                theta[(b * NQ + n0 + 4 * q + 1) * 32 + ci] = (unsigned short)(pv0 >> 16);
                theta[(b * NQ + n0 + 4 * q + 2) * 32 + ci] = (unsigned short)pv1;
                theta[(b * NQ + n0 + 4 * q + 3) * 32 + ci] = (unsigned short)(pv1 >> 16);
            } else {
                unsigned pv = pk2(fmaxf(acc[0], acc[1]), fmaxf(acc[2], acc[3]));
                if (p == 1) {
                    const int m0 = (n0 >> 1) + 2 * q;
                    phi[(b * MM + m0) * 32 + ci]     = (unsigned short)pv;
                    phi[(b * MM + m0 + 1) * 32 + ci] = (unsigned short)(pv >> 16);
                } else {
                    // m-local = wid*8 + 2q + {0,1}
                    *(unsigned int*)(gst + ci * 20 + wid * 8 + 2 * q) = pv;
                }
            }
        }
    }

    __syncthreads();
    {   // coalesced gT store: 16 m x 32 ci
        const int ci = tid >> 2;
        const int m4 = (tid & 3) * 4;
        u16x4 v = *(const u16x4*)(gst + ci * 20 + m4);
        *(u16x4*)(gT + (b * 32 + ci) * MM + rem * 16 + m4) = v;
    }
}

// ---------------------------------------------------------------------------
// Kernel 2: split-K flash attention, S^T form, 64 q-rows/wave, software-
// pipelined: PV of tile i-1 overlaps kf-load + exp2 of tile i. lsum via
// ones-row MFMA. Grid: 8*288 blocks x 128 thr (2 waves). 9 M-tiles each.
// ---------------------------------------------------------------------------
__global__ __launch_bounds__(128, 3) void attn_kernel(
    const unsigned short* __restrict__ theta, const unsigned short* __restrict__ phi,
    const unsigned short* __restrict__ gT,
    float* __restrict__ pacc, float* __restrict__ plsum)
{
    __shared__ unsigned short pld[2][64 * 64];   // per-wave P^T [n 64][m 64], XOR-swizzled

    const int tid  = threadIdx.x;
    const int w    = tid >> 6;
    const int lane = tid & 63;
    const int q  = lane >> 4;
    const int c  = lane & 15;
    const int xr = (c & 7) << 3;   // XOR swizzle for the m index

    const int ks  = blockIdx.x / 288;            // 0..7
    const int rem = blockIdx.x % 288;
    const int b   = rem / 72;
    const int nb  = (rem % 72) * 128 + w * 64;   // this wave's first Q row

    // Q B-frags: theta[n][ch], lane col n = c (per rt tile), k = q*8+j
    bf16x8 qf[4];
#pragma unroll
    for (int rt = 0; rt < 4; ++rt)
        qf[rt] = *(const bf16x8*)(theta + (b * NQ + nb + rt * 16 + c) * 32 + q * 8);

    // ones A-frag: row m=0 all-ones -> lanes with c==0 hold 1.0 in all k
    bf16x8 onef;
    {
        unsigned v = (c == 0) ? 0x3F803F80u : 0u;
        unsigned* op = (unsigned*)&onef;
        op[0] = v; op[1] = v; op[2] = v; op[3] = v;
    }

    const unsigned short* phiB = phi + (size_t)b * MM * 32;
    const unsigned short* gTB  = gT + (size_t)b * 32 * MM;
    unsigned short* myp = pld[w];

    f32x4 acc[4][2];    // [rt n-tile][s2 ci-tile]: col=n, row=ci
    f32x4 lacc[4];      // row0 = lsum per col n (lanes q=0, reg 0)
#pragma unroll
    for (int rt = 0; rt < 4; ++rt) {
        lacc[rt] = (f32x4){0.f, 0.f, 0.f, 0.f};
#pragma unroll
        for (int s2 = 0; s2 < 2; ++s2) acc[rt][s2] = (f32x4){0.f, 0.f, 0.f, 0.f};
    }

    const int mt0 = ks * 9;
    bf16x8 kf[4], vf[2][2];

    // ---- prologue: tile 0 S/exp/write ----
#pragma unroll
    for (int mct = 0; mct < 4; ++mct)
        kf[mct] = *(const bf16x8*)(phiB + (mt0 * 64 + mct * 16 + c) * 32 + q * 8);
#pragma unroll
    for (int s2 = 0; s2 < 2; ++s2)
#pragma unroll
        for (int st = 0; st < 2; ++st)
            vf[s2][st] = *(const bf16x8*)(gTB + (s2 * 16 + c) * MM + mt0 * 64 + st * 32 + q * 8);
#pragma unroll
    for (int mct = 0; mct < 4; ++mct) {
#pragma unroll
        for (int rt = 0; rt < 4; ++rt) {
            f32x4 z = {0.f, 0.f, 0.f, 0.f};
            f32x4 s = __builtin_amdgcn_mfma_f32_16x16x32_bf16(kf[mct], qf[rt], z, 0, 0, 0);
            uint2 hv = {pk2(__builtin_amdgcn_exp2f(s[0]), __builtin_amdgcn_exp2f(s[1])),
                        pk2(__builtin_amdgcn_exp2f(s[2]), __builtin_amdgcn_exp2f(s[3]))};
            *(uint2*)(myp + ((rt * 16 + c) << 6) + ((mct * 16 + 4 * q) ^ xr)) = hv;
        }
    }

    // ---- steady state: PV(i-1) || kf-load(i), then S(i)/exp/write(i) ----
    for (int mi = 1; mi < 9; ++mi) {
        const int m0 = (mt0 + mi) * 64;

        // kf(i): L2 latency hides under the PV MFMAs below
#pragma unroll
        for (int mct = 0; mct < 4; ++mct)
            kf[mct] = *(const bf16x8*)(phiB + (m0 + mct * 16 + c) * 32 + q * 8);

        // PV(i-1): reads pld (program-order before this tile's writes; same-
        // wave DS is in-order so the single buffer is WAR-safe)
#pragma unroll
        for (int rt = 0; rt < 4; ++rt) {
#pragma unroll
            for (int st = 0; st < 2; ++st) {
                bf16x8 pf = *(const bf16x8*)(myp + ((rt * 16 + c) << 6) + ((st * 32 + q * 8) ^ xr));
#pragma unroll
                for (int s2 = 0; s2 < 2; ++s2)
                    acc[rt][s2] = __builtin_amdgcn_mfma_f32_16x16x32_bf16(vf[s2][st], pf, acc[rt][s2], 0, 0, 0);
                lacc[rt] = __builtin_amdgcn_mfma_f32_16x16x32_bf16(onef, pf, lacc[rt], 0, 0, 0);
            }
        }

        // vf(i): consumed by next iteration's PV
#pragma unroll
        for (int s2 = 0; s2 < 2; ++s2)
#pragma unroll
            for (int st = 0; st < 2; ++st)
                vf[s2][st] = *(const bf16x8*)(gTB + (s2 * 16 + c) * MM + m0 + st * 32 + q * 8);

        // S(i) + exp2 + pack + P^T write (XOR-swizzled, 2-way)
#pragma unroll
        for (int mct = 0; mct < 4; ++mct) {
#pragma unroll
            for (int rt = 0; rt < 4; ++rt) {
                f32x4 z = {0.f, 0.f, 0.f, 0.f};
                f32x4 s = __builtin_amdgcn_mfma_f32_16x16x32_bf16(kf[mct], qf[rt], z, 0, 0, 0);
                uint2 hv = {pk2(__builtin_amdgcn_exp2f(s[0]), __builtin_amdgcn_exp2f(s[1])),
                            pk2(__builtin_amdgcn_exp2f(s[2]), __builtin_amdgcn_exp2f(s[3]))};
                *(uint2*)(myp + ((rt * 16 + c) << 6) + ((mct * 16 + 4 * q) ^ xr)) = hv;
            }
        }
    }

    // ---- epilogue: PV of last tile ----
#pragma unroll
    for (int rt = 0; rt < 4; ++rt) {
#pragma unroll
        for (int st = 0; st < 2; ++st) {
            bf16x8 pf = *(const bf16x8*)(myp + ((rt * 16 + c) << 6) + ((st * 32 + q * 8) ^ xr));
#pragma unroll
            for (int s2 = 0; s2 < 2; ++s2)
                acc[rt][s2] = __builtin_amdgcn_mfma_f32_16x16x32_bf16(vf[s2][st], pf, acc[rt][s2], 0, 0, 0);
            lacc[rt] = __builtin_amdgcn_mfma_f32_16x16x32_bf16(onef, pf, lacc[rt], 0, 0, 0);
        }
    }

    // accumulate partials: pacc[b][ci][n], 16-lane-contiguous per quad row
#pragma unroll
    for (int rt = 0; rt < 4; ++rt)
#pragma unroll
        for (int s2 = 0; s2 < 2; ++s2)
#pragma unroll
            for (int r = 0; r < 4; ++r)
                atomicAdd(&pacc[(size_t)(b * 32 + s2 * 16 + 4 * q + r) * NQ + nb + rt * 16 + c],
                          acc[rt][s2][r]);
    if (lane < 16) {   // lsum lives in D row 0: lanes q=0, reg 0
#pragma unroll
        for (int rt = 0; rt < 4; ++rt)
            atomicAdd(&plsum[(size_t)b * NQ + nb + rt * 16 + lane], lacc[rt][0]);
    }
}

// ---------------------------------------------------------------------------
// Kernel 3: y^T = pacc/plsum -> LDS [ci][n] -> out = w_out.y^T + b + x.
// Grid: 1152 blocks x 128 thr (2 waves x 16 n), 32-n tiles.
// ---------------------------------------------------------------------------
__global__ __launch_bounds__(128, 4) void reduce_kernel(
    const float* __restrict__ pacc, const float* __restrict__ plsum,
    const float* __restrict__ w_out, const float* __restrict__ b_out,
    const float* __restrict__ x, float* __restrict__ out)
{
    __shared__ unsigned short yld[32 * 36];   // y^T tile: [ci 32][n 32+4]

    const int tid = threadIdx.x;
    const int b   = blockIdx.x / 288;
    const int nb  = (blockIdx.x % 288) * 32;

    // phase 1: coalesced read of pacc/plsum, divide, bf16, stage to LDS
    {
        const int ci = tid >> 2;
        const int n8 = (tid & 3) * 8;
        const float* pr = pacc + (size_t)(b * 32 + ci) * NQ + nb + n8;
        f32x4 a0 = *(const f32x4*)pr;
        f32x4 a1 = *(const f32x4*)(pr + 4);
        const float* lr = plsum + (size_t)b * NQ + nb + n8;
        f32x4 l0 = *(const f32x4*)lr;
        f32x4 l1 = *(const f32x4*)(lr + 4);
        uint2 v0 = {pk2(a0[0] / l0[0], a0[1] / l0[1]), pk2(a0[2] / l0[2], a0[3] / l0[3])};
        uint2 v1 = {pk2(a1[0] / l1[0], a1[1] / l1[1]), pk2(a1[2] / l1[2], a1[3] / l1[3])};
        *(uint2*)(yld + ci * 36 + n8)     = v0;
        *(uint2*)(yld + ci * 36 + n8 + 4) = v1;
    }
    __syncthreads();

    // phase 2: out-projection MFMA. A=w_out (rows chn, k=ci), B=y^T.
    const int w    = tid >> 6;
    const int lane = tid & 63;
    const int q = lane >> 4;
    const int c = lane & 15;

    bf16x8 wof[4];
#pragma unroll
    for (int ct = 0; ct < 4; ++ct) {
        const float* wsrc = w_out + (ct * 16 + c) * 32 + q * 8;
        f32x4 w0 = *(const f32x4*)wsrc;
        f32x4 w1 = *(const f32x4*)(wsrc + 4);
        unsigned* wk = (unsigned*)&wof[ct];
        wk[0] = pk2(w0[0], w0[1]); wk[1] = pk2(w0[2], w0[3]);
        wk[2] = pk2(w1[0], w1[1]); wk[3] = pk2(w1[2], w1[3]);
    }

    // B-frag: B[k=ci=q*8+j][col n=w*16+c] from yld[ci][n]
    bf16x8 yf;
    {
        unsigned short* yp = (unsigned short*)&yf;
#pragma unroll
        for (int j = 0; j < 8; ++j)
            yp[j] = yld[(q * 8 + j) * 36 + w * 16 + c];
    }

#pragma unroll
    for (int ct = 0; ct < 4; ++ct) {
        f32x4 z = {0.f, 0.f, 0.f, 0.f};
        f32x4 o = __builtin_amdgcn_mfma_f32_16x16x32_bf16(wof[ct], yf, z, 0, 0, 0);
#pragma unroll
        for (int r = 0; r < 4; ++r) {
            const int chn = ct * 16 + 4 * q + r;
            const size_t addr = (size_t)(b * 64 + chn) * NQ + nb + w * 16 + c;
            out[addr] = o[r] + b_out[chn] + x[addr];
        }
    }
}

extern "C" void kernel_launch(void* const* d_in, const int* in_sizes, int n_in,
                              void* d_out, int out_size, void* d_ws, size_t ws_size,
                              hipStream_t stream) {
    const float* x       = (const float*)d_in[0];
    const float* w_theta = (const float*)d_in[1];
    const float* b_theta = (const float*)d_in[2];
    const float* w_phi   = (const float*)d_in[3];
    const float* b_phi   = (const float*)d_in[4];
    const float* w_g     = (const float*)d_in[5];
    const float* b_g     = (const float*)d_in[6];
    const float* w_out   = (const float*)d_in[7];
    const float* b_out   = (const float*)d_in[8];
    float* out = (float*)d_out;

    // ws layout (bytes):
    //   theta bf16 [4][9216][32] : 2,359,296
    //   phi   bf16 [4][4608][32] : 1,179,648
    //   gT    bf16 [4][32][4608] : 1,179,648
    //   pacc  f32  [4][32][9216] : 4,718,592   (atomic accumulators)
    //   plsum f32  [4][9216]     :   147,456   (contiguous with pacc)
    unsigned short* theta = (unsigned short*)d_ws;
    unsigned short* phi   = theta + 4 * NQ * 32;
    unsigned short* gT    = phi + 4 * MM * 32;
    float* pacc  = (float*)(gT + 4 * 32 * MM);
    float* plsum = pacc + (size_t)4 * 32 * NQ;

    proj_kernel<<<1152, 128, 0, stream>>>(x, w_theta, b_theta, w_phi, b_phi,
                                          w_g, b_g, theta, phi, gT, pacc);
    attn_kernel<<<8 * 288, 128, 0, stream>>>(theta, phi, gT, pacc, plsum);
    reduce_kernel<<<1152, 128, 0, stream>>>(pacc, plsum, w_out, b_out, x, out);
}